// Round 1
// 953.937 us; speedup vs baseline: 1.0905x; 1.0905x over previous
//
#include <hip/hip_runtime.h>
#include <hip/hip_bf16.h>
#include <stdint.h>

// Problem constants
#define NB 32
#define NS 512
#define ND 1024
#define NH 16
#define NDK 64
// M = NB*NS = 16384, K = ND = 1024, N = 3*ND = 3072

typedef unsigned short u16t;
typedef __bf16 bf16x8 __attribute__((ext_vector_type(8)));
typedef float f32x4 __attribute__((ext_vector_type(4)));
typedef u16t u16x8 __attribute__((ext_vector_type(8)));
typedef u16t u16x4 __attribute__((ext_vector_type(4)));

__device__ __forceinline__ u16t f2bf(float f) {
    uint32_t u = __float_as_uint(f);
    u += 0x7FFFu + ((u >> 16) & 1u);   // RNE
    return (u16t)(u >> 16);
}

// async global->LDS, 16B per lane. LDS dest must be wave-uniform base +
// lane*16 — caller guarantees the layout.
__device__ __forceinline__ void gload_lds16(const u16t* g, u16t* l) {
    __builtin_amdgcn_global_load_lds(
        (const __attribute__((address_space(1))) unsigned int*)g,
        (__attribute__((address_space(3))) unsigned int*)l, 16, 0, 0);
}

// ---------------------------------------------------------------------------
// Kernel 1: cast Q -> X (bf16), concat-cast Wq/Wk/Wv -> Wc (bf16 [3072][1024])
// ---------------------------------------------------------------------------
__global__ __launch_bounds__(256) void cast_kernel(
    const float4* __restrict__ Q, const float4* __restrict__ Wq,
    const float4* __restrict__ Wk, const float4* __restrict__ Wv,
    u16t* __restrict__ X, u16t* __restrict__ Wc)
{
    const int64_t NQ = 16777216 / 4;   // float4 groups in Q
    const int64_t NW = 1048576 / 4;    // float4 groups per W
    const int64_t total = NQ + 3 * NW;
    for (int64_t i = (int64_t)blockIdx.x * 256 + threadIdx.x; i < total;
         i += (int64_t)gridDim.x * 256) {
        float4 v;
        u16t* dst;
        if (i < NQ) {
            v = Q[i];
            dst = X + i * 4;
        } else {
            int64_t j = i - NQ;
            int sel = (int)(j / NW);
            int64_t t = j % NW;
            v = (sel == 0 ? Wq : sel == 1 ? Wk : Wv)[t];
            dst = Wc + (sel * NW + t) * 4;
        }
        u16x4 o;
        o.x = f2bf(v.x); o.y = f2bf(v.y); o.z = f2bf(v.z); o.w = f2bf(v.w);
        *(u16x4*)dst = o;
    }
}

// ---------------------------------------------------------------------------
// Kernel 2: QKV projection GEMM. C[m][n] = sum_k X[m][k] * Wc[n][k]  (+bias)
// 128x128 tile, BK=32, 4 waves each 64x64 via 4x4 grid of 16x16x32 MFMA.
// Staging via global_load_lds width=16 (m97 recipe). LDS byte offset of
// segment `tid` is exactly tid*16 => wave-uniform base + lane*16. ✓
// Epilogue: +bias, q scaled by 0.125, bf16 store to [B,H,S,DK].
// ---------------------------------------------------------------------------
__global__ __launch_bounds__(256) void gemm_qkv(
    const u16t* __restrict__ X, const u16t* __restrict__ Wc,
    const float* __restrict__ bq, const float* __restrict__ bk,
    const float* __restrict__ bv,
    u16t* __restrict__ Qp, u16t* __restrict__ Kp, u16t* __restrict__ Vp)
{
    __shared__ __align__(16) u16t As[128 * 32];
    __shared__ __align__(16) u16t Bs[128 * 32];
    const int tid = threadIdx.x;
    const int lane = tid & 63, wave = tid >> 6;
    const int cl = lane & 15, g4 = lane >> 4;
    const int m0 = blockIdx.x * 128;
    const int n0 = blockIdx.y * 128;
    const int wm = (wave & 1) * 64, wn = (wave >> 1) * 64;

    f32x4 acc[4][4] = {};

    // staging: 512 16B segments per tile; thread owns segs tid and tid+256
    const int r0 = tid >> 2, sg0 = tid & 3;
    const int r1 = r0 + 64;
    const u16t* xrow0 = X  + (size_t)(m0 + r0) * 1024 + sg0 * 8;
    const u16t* xrow1 = X  + (size_t)(m0 + r1) * 1024 + sg0 * 8;
    const u16t* wrow0 = Wc + (size_t)(n0 + r0) * 1024 + sg0 * 8;
    const u16t* wrow1 = Wc + (size_t)(n0 + r1) * 1024 + sg0 * 8;
    u16t* asd0 = &As[r0 * 32 + sg0 * 8];
    u16t* asd1 = &As[r1 * 32 + sg0 * 8];
    u16t* bsd0 = &Bs[r0 * 32 + sg0 * 8];
    u16t* bsd1 = &Bs[r1 * 32 + sg0 * 8];

    for (int kt = 0; kt < 1024; kt += 32) {
        __syncthreads();
        gload_lds16(xrow0 + kt, asd0);
        gload_lds16(xrow1 + kt, asd1);
        gload_lds16(wrow0 + kt, bsd0);
        gload_lds16(wrow1 + kt, bsd1);
        __syncthreads();

        bf16x8 af[4], bf_[4];
#pragma unroll
        for (int t = 0; t < 4; ++t) {
            af[t]  = *(const bf16x8*)&As[(wm + t * 16 + cl) * 32 + g4 * 8];
            bf_[t] = *(const bf16x8*)&Bs[(wn + t * 16 + cl) * 32 + g4 * 8];
        }
#pragma unroll
        for (int mt = 0; mt < 4; ++mt)
#pragma unroll
            for (int nt = 0; nt < 4; ++nt)
                acc[mt][nt] = __builtin_amdgcn_mfma_f32_16x16x32_bf16(
                    af[mt], bf_[nt], acc[mt][nt], 0, 0, 0);
    }

    // epilogue
    const int w = n0 >> 10;  // 0:q 1:k 2:v (uniform per block: 128 | 1024)
    const float* bias = (w == 0) ? bq : (w == 1) ? bk : bv;
    u16t* outp = (w == 0) ? Qp : (w == 1) ? Kp : Vp;
    const float scale = (w == 0) ? 0.125f : 1.0f;
    const int nfbase = (n0 & 1023) + wn;
#pragma unroll
    for (int nt = 0; nt < 4; ++nt) {
        const int nf = nfbase + nt * 16 + cl;   // feature 0..1023
        const int h = nf >> 6, dk = nf & 63;
        const float bval = bias[nf];
#pragma unroll
        for (int mt = 0; mt < 4; ++mt) {
#pragma unroll
            for (int r = 0; r < 4; ++r) {
                const int m = m0 + wm + mt * 16 + g4 * 4 + r;
                const int b = m >> 9, s = m & 511;
                float val = (acc[mt][nt][r] + bval) * scale;
                outp[((size_t)(b * NH + h) * NS + s) * NDK + dk] = f2bf(val);
            }
        }
    }
}

// ---------------------------------------------------------------------------
// Kernel 3: transpose V [B,H,S,DK] -> Vt [B,H,DK,S] (bf16), LDS-tiled 64x64
// ---------------------------------------------------------------------------
__global__ __launch_bounds__(256) void transpose_v(
    const u16t* __restrict__ Vp, u16t* __restrict__ Vt)
{
    __shared__ __align__(16) u16t T[64 * 72];
    const int bh = blockIdx.x;   // 0..511
    const int sc = blockIdx.y;   // 0..7  (64-row chunk of S)
    const u16t* src = Vp + (size_t)bh * NS * NDK + (size_t)sc * 64 * NDK;
    u16t* dst = Vt + (size_t)bh * NDK * NS + sc * 64;

#pragma unroll
    for (int i = 0; i < 2; ++i) {
        int c = threadIdx.x + i * 256;       // 0..511
        int row = c >> 3, sg = c & 7;
        *(u16x8*)&T[row * 72 + sg * 8] = *(const u16x8*)&src[row * 64 + sg * 8];
    }
    __syncthreads();
#pragma unroll
    for (int i = 0; i < 2; ++i) {
        int c = threadIdx.x + i * 256;
        int dk = c >> 3, sg = c & 7;
        u16x8 v;
#pragma unroll
        for (int j = 0; j < 8; ++j) v[j] = T[(sg * 8 + j) * 72 + dk];
        *(u16x8*)&dst[(size_t)dk * NS + sg * 8] = v;
    }
}

// ---------------------------------------------------------------------------
// Kernel 4: fused attention per (b, h, 64 q-rows). Wave owns 16 q rows.
// Pass 1: E[kt] = exp(q.k) masked, kept in 128 VGPRs; row sums via shfl_xor.
// Pass 2: normalize -> write attn; P->LDS->A-frag; PV MFMA with Vt B-frags.
// Pst is per-wave private => NO __syncthreads needed (intra-wave LDS RAW is
// ordered by compiler-inserted lgkmcnt waits).
//
// R1 changes:
//  * XCD-pin remap: the 8 qt-blocks sharing one (b,h)'s K/Vt tiles now map
//    to the SAME XCD (bh = ((raw>>6)<<3)|(raw&7), qt = (raw>>3)&7), so K/Vt
//    are fetched from HBM once per XCD-resident bh instead of 8x.
//  * length-skip: wave-uniform guards on the unrolled kt / g loops (len is
//    uniform per block). Compile-time indices keep E[] in registers.
//    Masked tail of attn written as exact zeros with float4 stores.
// ---------------------------------------------------------------------------
__global__ __launch_bounds__(256) void attn_kernel(
    const u16t* __restrict__ Qp, const u16t* __restrict__ Kp,
    const u16t* __restrict__ Vt, const int* __restrict__ length,
    float* __restrict__ ctx, float* __restrict__ attn)
{
    __shared__ __align__(16) u16t Pst[4][16 * 40];  // per-wave, row stride 40
    const int tid = threadIdx.x, lane = tid & 63, wave = tid >> 6;
    const int cl = lane & 15, g4 = lane >> 4;
    const int raw = blockIdx.x;          // 0..4095
    const int bh = ((raw >> 6) << 3) | (raw & 7);  // XCD-pinned: bh%8 == raw%8
    const int qt = (raw >> 3) & 7;
    const int b = bh >> 4;
    const int len = length[b];
    const int nkt = (len + 15) >> 4;     // valid 16-key groups, 1..32
    const int ng  = (len + 31) >> 5;     // valid 32-key groups, 1..16
    const int qbase = qt * 64 + wave * 16;

    const u16t* qptr = Qp + (size_t)bh * NS * NDK + (size_t)qbase * NDK;
    const u16t* kptr = Kp + (size_t)bh * NS * NDK;
    const u16t* vtptr = Vt + (size_t)bh * NDK * NS;

    // Q A-frags (dk 0..31 and 32..63); q already scaled by 1/8
    const bf16x8 aq0 = *(const bf16x8*)&qptr[cl * 64 + g4 * 8];
    const bf16x8 aq1 = *(const bf16x8*)&qptr[cl * 64 + 32 + g4 * 8];

    f32x4 E[32];
    float rs[4] = {0.f, 0.f, 0.f, 0.f};
#pragma unroll
    for (int kt = 0; kt < 32; ++kt) {
        if (kt < nkt) {                  // wave-uniform (len uniform in block)
            const bf16x8 bk0 = *(const bf16x8*)&kptr[(kt * 16 + cl) * 64 + g4 * 8];
            const bf16x8 bk1 = *(const bf16x8*)&kptr[(kt * 16 + cl) * 64 + 32 + g4 * 8];
            f32x4 sc = {0.f, 0.f, 0.f, 0.f};
            sc = __builtin_amdgcn_mfma_f32_16x16x32_bf16(aq0, bk0, sc, 0, 0, 0);
            sc = __builtin_amdgcn_mfma_f32_16x16x32_bf16(aq1, bk1, sc, 0, 0, 0);
            const bool valid = (kt * 16 + cl) < len;   // C layout: col = lane&15
            f32x4 e;
#pragma unroll
            for (int r = 0; r < 4; ++r) {
                float ev = valid ? __expf(sc[r]) : 0.0f;
                e[r] = ev;
                rs[r] += ev;
            }
            E[kt] = e;
        } else {
            E[kt] = (f32x4){0.f, 0.f, 0.f, 0.f};
        }
    }

    // row-sum reduce across the 16 lanes sharing a row group (low 4 lane bits)
#pragma unroll
    for (int r = 0; r < 4; ++r) {
        float v = rs[r];
        v += __shfl_xor(v, 1);
        v += __shfl_xor(v, 2);
        v += __shfl_xor(v, 4);
        v += __shfl_xor(v, 8);
        rs[r] = 1.0f / (v + 1e-8f);
    }

    f32x4 cacc[4] = {};
    float* attnw = attn + ((size_t)bh * NS + qbase) * NS;
#pragma unroll
    for (int g = 0; g < 16; ++g) {       // 32-key groups
        if (g < ng) {                    // wave-uniform guard
#pragma unroll
            for (int t = 0; t < 2; ++t) {
                const int kt = g * 2 + t;
#pragma unroll
                for (int r = 0; r < 4; ++r) {
                    const float a = E[kt][r] * rs[r];
                    attnw[(size_t)(g4 * 4 + r) * NS + kt * 16 + cl] = a;
                    Pst[wave][(g4 * 4 + r) * 40 + t * 16 + cl] = f2bf(a);
                }
            }
            // P A-frag: rows=q (lane&15), k=key offset g4*8..+8 within the 32
            const bf16x8 ap = *(const bf16x8*)&Pst[wave][cl * 40 + g4 * 8];
#pragma unroll
            for (int nt = 0; nt < 4; ++nt) {
                const bf16x8 bv = *(const bf16x8*)
                    &vtptr[(size_t)(nt * 16 + cl) * NS + g * 32 + g4 * 8];
                cacc[nt] = __builtin_amdgcn_mfma_f32_16x16x32_bf16(
                    ap, bv, cacc[nt], 0, 0, 0);
            }
        }
    }

    // zero tail of attn (cols >= ng*32 are exactly 0 after masking+normalize)
    {
        const int zr = lane >> 2;            // 16 rows per wave
        const int zc = (lane & 3) * 4;       // 4 float4 lanes per row
        const float4 z = {0.f, 0.f, 0.f, 0.f};
        for (int c = ng * 32; c < NS; c += 16)
            *(float4*)&attnw[(size_t)zr * NS + c + zc] = z;
    }

    // context write: [b, s, h*64+dk]
    float* cw = ctx + ((size_t)b * NS + qbase) * ND + (bh & 15) * NDK;
#pragma unroll
    for (int nt = 0; nt < 4; ++nt)
#pragma unroll
        for (int r = 0; r < 4; ++r)
            cw[(size_t)(g4 * 4 + r) * ND + nt * 16 + cl] = cacc[nt][r];
}

// ---------------------------------------------------------------------------
extern "C" void kernel_launch(void* const* d_in, const int* in_sizes, int n_in,
                              void* d_out, int out_size, void* d_ws, size_t ws_size,
                              hipStream_t stream)
{
    const float* Q   = (const float*)d_in[0];
    const float* Wq  = (const float*)d_in[1];
    const float* bq  = (const float*)d_in[2];
    const float* Wk  = (const float*)d_in[3];
    const float* bk  = (const float*)d_in[4];
    const float* Wv  = (const float*)d_in[5];
    const float* bv  = (const float*)d_in[6];
    const int* length = (const int*)d_in[7];

    float* ctx  = (float*)d_out;                     // 16,777,216 floats
    float* attn = (float*)d_out + 16777216;          // 134,217,728 floats

    char* ws = (char*)d_ws;
    const size_t szX  = 33554432;   // 16.8M bf16
    const size_t szW  = 6291456;    // 3.1M bf16
    const size_t szP  = 33554432;   // each of Qp/Kp/Vp/Vt

    u16t *X, *Wc, *Qp, *Kp, *Vp, *Vt;
    const size_t needA = szX + szW + 4 * szP;        // ~174 MB
    if (ws_size >= needA) {
        X  = (u16t*)(ws);
        Wc = (u16t*)(ws + szX);
        Qp = (u16t*)(ws + szX + szW);
        Kp = (u16t*)(ws + szX + szW + szP);
        Vp = (u16t*)(ws + szX + szW + 2 * szP);
        Vt = (u16t*)(ws + szX + szW + 3 * szP);
    } else {
        // fallback: stage X/Wc in the attn output region (dead before attn
        // kernel runs); qkv buffers in ws (needs ~134 MB)
        X  = (u16t*)(attn);
        Wc = (u16t*)((char*)attn + szX);
        Qp = (u16t*)(ws);
        Kp = (u16t*)(ws + szP);
        Vp = (u16t*)(ws + 2 * szP);
        Vt = (u16t*)(ws + 3 * szP);
    }

    cast_kernel<<<dim3(2048), dim3(256), 0, stream>>>(
        (const float4*)Q, (const float4*)Wq, (const float4*)Wk,
        (const float4*)Wv, X, Wc);

    gemm_qkv<<<dim3(128, 24), dim3(256), 0, stream>>>(
        X, Wc, bq, bk, bv, Qp, Kp, Vp);

    transpose_v<<<dim3(512, 8), dim3(256), 0, stream>>>(Vp, Vt);

    attn_kernel<<<dim3(4096), dim3(256), 0, stream>>>(
        Qp, Kp, Vt, length, ctx, attn);
}